// Round 6
// baseline (306.429 us; speedup 1.0000x reference)
//
#include <hip/hip_runtime.h>

typedef __attribute__((ext_vector_type(8))) short short8;
typedef __attribute__((ext_vector_type(4))) float floatx4;

#define EMB 1024
#define HEADS 16
#define HDIM 64
#define BATCH 4
#define SEQ 2048
#define ROWS (BATCH * SEQ)   // 8192

__device__ __forceinline__ unsigned short f2bf(float f) {
  unsigned u = __float_as_uint(f);
  u += 0x7fffu + ((u >> 16) & 1u);   // round-to-nearest-even
  return (unsigned short)(u >> 16);
}

__device__ __forceinline__ unsigned pk2bf(float lo, float hi) {
#if __has_builtin(__builtin_amdgcn_cvt_pk_bf16_f32)
  auto v = __builtin_amdgcn_cvt_pk_bf16_f32(lo, hi);
  return __builtin_bit_cast(unsigned, v);
#else
  return (unsigned)f2bf(lo) | ((unsigned)f2bf(hi) << 16);
#endif
}

__device__ __forceinline__ float fexp2(float x) {
#if __has_builtin(__builtin_amdgcn_exp2f)
  return __builtin_amdgcn_exp2f(x);
#else
  return __builtin_exp2f(x);
#endif
}

__device__ __forceinline__ void gload16(const void* g, void* l) {
  __builtin_amdgcn_global_load_lds(
      (const __attribute__((address_space(1))) unsigned int*)g,
      (__attribute__((address_space(3))) unsigned int*)l, 16, 0, 0);
}

// ---------------- fp32 -> bf16 convert (row-major copy) ----------------
__global__ void cvt_kernel(const float* __restrict__ in,
                           unsigned short* __restrict__ out, int n) {
  int i = (blockIdx.x * blockDim.x + threadIdx.x) * 4;
  if (i < n) {
    float4 f = *reinterpret_cast<const float4*>(in + i);
    ushort4 o;
    o.x = f2bf(f.x); o.y = f2bf(f.y); o.z = f2bf(f.z); o.w = f2bf(f.w);
    *reinterpret_cast<ushort4*>(out + i) = o;
  }
}

// ---------------- fp32 [R][C] -> bf16 [C][R] transpose ----------------
__global__ __launch_bounds__(256) void cvt_T_kernel(
    const float* __restrict__ in, unsigned short* __restrict__ out, int R, int C) {
  __shared__ float t[32][33];
  const int tx = threadIdx.x & 31, ty = threadIdx.x >> 5;  // 32 x 8
  const int c0 = blockIdx.x * 32, r0 = blockIdx.y * 32;
#pragma unroll
  for (int j = 0; j < 4; ++j)
    t[ty + j * 8][tx] = in[(size_t)(r0 + ty + j * 8) * C + c0 + tx];
  __syncthreads();
#pragma unroll
  for (int j = 0; j < 4; ++j)
    out[(size_t)(c0 + ty + j * 8) * R + r0 + tx] = f2bf(t[tx][ty + j * 8]);
}

// ---------------- bf16 MFMA GEMM: C = A[M,K] @ Bt[N,K]^T + bias ----------------
// LDS XOR-swizzled (octet ^= row&7): staging stays contiguous-per-lane (gload16
// requirement), fragment b128 reads spread across all 32 banks (measured: 0 conflicts).
// EPI=0: scatter q/k [B,H,T,D] (q scaled 0.125*log2e), v transposed [B,H,D,T].
// EPI=1: fp32 out.
#define BM 128
#define BN 128
#define BK 64
#define QSCALE 0.18033688011116016f   // 0.125 * log2(e): softmax via exp2

template <int EPI>
__global__ __launch_bounds__(256) void gemm_bf16(
    const unsigned short* __restrict__ A, const unsigned short* __restrict__ Bt,
    const float* __restrict__ bias,
    unsigned short* __restrict__ qo, unsigned short* __restrict__ ko,
    unsigned short* __restrict__ vo, float* __restrict__ fo,
    int M, int N, int K) {
  __shared__ unsigned short Al[BM * BK];   // [row][k], unpadded, swizzled
  __shared__ unsigned short Bl[BN * BK];   // [n][k], unpadded, swizzled
  const int tid = threadIdx.x;
  const int wid = tid >> 6, lane = tid & 63;
  const int quad = lane >> 4, l16 = lane & 15;
  const int wr = wid >> 1, wc = wid & 1;
  const int bm = blockIdx.y * BM, bn = blockIdx.x * BN;
  const int lrow = lane >> 3;                   // staging row within 8-row chunk
  const int srow = wid * 8 + lrow;              // staging row within 32-row slab
  const int soct = ((lane & 7) ^ lrow) * 8;     // XOR-swizzled source k-octet

  floatx4 acc[4][4] = {};

  for (int k0 = 0; k0 < K; k0 += BK) {
    __syncthreads();
#pragma unroll
    for (int it = 0; it < 4; ++it) {
      gload16(&A[(size_t)(bm + it * 32 + srow) * K + k0 + soct],
              &Al[(wid * 8 + it * 32) * BK]);
      gload16(&Bt[(size_t)(bn + it * 32 + srow) * K + k0 + soct],
              &Bl[(wid * 8 + it * 32) * BK]);
    }
    __syncthreads();
#pragma unroll
    for (int kk = 0; kk < BK; kk += 32) {
      const int swz = ((((kk >> 3) + quad) ^ (l16 & 7)) << 3);
      short8 af[4], bfv[4];
#pragma unroll
      for (int i = 0; i < 4; ++i)
        af[i] = *reinterpret_cast<const short8*>(
            &Al[(wr * 64 + i * 16 + l16) * BK + swz]);
#pragma unroll
      for (int j = 0; j < 4; ++j)
        bfv[j] = *reinterpret_cast<const short8*>(
            &Bl[(wc * 64 + j * 16 + l16) * BK + swz]);
#pragma unroll
      for (int i = 0; i < 4; ++i)
#pragma unroll
        for (int j = 0; j < 4; ++j)
          acc[i][j] = __builtin_amdgcn_mfma_f32_16x16x32_bf16(af[i], bfv[j],
                                                              acc[i][j], 0, 0, 0);
    }
  }

  // epilogue: D[row=quad*4+r][col=l16] per 16x16 tile
#pragma unroll
  for (int j = 0; j < 4; ++j) {
    const int n = bn + wc * 64 + j * 16 + l16;
    const float bv = bias[n];
    if (EPI == 0) {
      const int which = n >> 10, cc = n & 1023;
      const int hh = cc >> 6, dd = cc & 63;
#pragma unroll
      for (int i = 0; i < 4; ++i) {
        const int m0 = bm + wr * 64 + i * 16 + quad * 4;
        const int bb = m0 >> 11, tt = m0 & 2047;
        if (which == 2) {
          ushort4 pk;
          pk.x = f2bf(acc[i][j][0] + bv);
          pk.y = f2bf(acc[i][j][1] + bv);
          pk.z = f2bf(acc[i][j][2] + bv);
          pk.w = f2bf(acc[i][j][3] + bv);
          *reinterpret_cast<ushort4*>(
              &vo[(((size_t)bb * HEADS + hh) * HDIM + dd) * SEQ + tt]) = pk;
        } else {
          unsigned short* dst = (which == 0) ? qo : ko;
          const float sc = (which == 0) ? QSCALE : 1.0f;
          const size_t base = (((size_t)bb * HEADS + hh) * SEQ + tt) * HDIM + dd;
#pragma unroll
          for (int r = 0; r < 4; ++r)
            dst[base + (size_t)r * HDIM] = f2bf((acc[i][j][r] + bv) * sc);
        }
      }
    } else {
#pragma unroll
      for (int i = 0; i < 4; ++i) {
        const int m0 = bm + wr * 64 + i * 16 + quad * 4;
#pragma unroll
        for (int r = 0; r < 4; ++r)
          fo[(size_t)(m0 + r) * N + n] = acc[i][j][r] + bv;
      }
    }
  }
}

// ---------------- flash attention (causal, unnormalized exp2 softmax) --------------
// One q-tile (128 rows) per block, heavy tiles (qt=15-bx) dispatched first.
// Q fragments held in REGISTERS (A-layout chunks are contiguous 16B in global [T,D]).
// K/V double-buffered in LDS, one barrier per k-tile (prefetch crosses the barrier).
// LDS = 52,224 B -> 3 blocks/CU; 1024 blocks total.
#define LDSP 76
__global__ __launch_bounds__(256, 3) void attn_kernel(
    const unsigned short* __restrict__ q, const unsigned short* __restrict__ k,
    const unsigned short* __restrict__ vt, unsigned short* __restrict__ att) {
  __shared__ unsigned short Ks[2][64 * 64];
  __shared__ unsigned short Vt[2][64 * 64];  // [d][key]
  __shared__ unsigned short Ps[128 * LDSP];  // [q][key], wave-private 32-row slabs
  const int tid = threadIdx.x, wid = tid >> 6, lane = tid & 63;
  const int quad = lane >> 4, l16 = lane & 15;
  const int lrow = lane >> 3;                       // row within 8-row chunk
  const int loct = ((lane & 7) ^ lrow) * 8;         // XOR-swizzled source octet
  const int qt = 15 - (int)blockIdx.x;              // heavy tiles dispatch first
  const int h = blockIdx.y, b = blockIdx.z;
  const size_t hb = ((size_t)b * HEADS + h) * SEQ * HDIM;  // q,k row base
  const size_t hv = ((size_t)b * HEADS + h) * HDIM * SEQ;  // vt row base
  const int qbase = qt * 128 + wid * 32;            // this wave's first q row

  // Q fragments direct to registers: A[m=l16][k=quad*8+j] is contiguous 16B in [T,D]
  short8 qf[2][2];
#pragma unroll
  for (int i = 0; i < 2; ++i)
#pragma unroll
    for (int c = 0; c < 2; ++c)
      qf[i][c] = *reinterpret_cast<const short8*>(
          &q[hb + (size_t)(qbase + i * 16 + l16) * HDIM + c * 32 + quad * 8]);

  // stage K/V tile 0 into buf 0
#pragma unroll
  for (int it = 0; it < 2; ++it) {
    gload16(&k[hb + (size_t)(wid * 16 + it * 8 + lrow) * HDIM + loct],
            &Ks[0][(wid * 16 + it * 8) * 64]);
    gload16(&vt[hv + (size_t)(wid * 16 + it * 8 + lrow) * SEQ + loct],
            &Vt[0][(wid * 16 + it * 8) * 64]);
  }

  floatx4 o[2][4] = {};
  float lsum[2][4] = {};

  const int ntile = 2 * qt + 2;
  for (int kt = 0; kt < ntile; ++kt) {
    __syncthreads();  // buf[kt&1] staged (per-wave vmcnt drained); prior readers done
    if (kt + 1 < ntile) {   // prefetch next tile into the other buffer
      const int nb = (kt + 1) & 1;
#pragma unroll
      for (int it = 0; it < 2; ++it) {
        gload16(&k[hb + (size_t)((kt + 1) * 64 + wid * 16 + it * 8 + lrow) * HDIM + loct],
                &Ks[nb][(wid * 16 + it * 8) * 64]);
        gload16(&vt[hv + (size_t)(wid * 16 + it * 8 + lrow) * SEQ + (kt + 1) * 64 + loct],
                &Vt[nb][(wid * 16 + it * 8) * 64]);
      }
    }
    if (kt * 64 > qbase + 31) continue;   // wave fully masked this k-tile
    const int cb = kt & 1;

#pragma unroll
    for (int i = 0; i < 2; ++i) {
      const int arow = wid * 32 + i * 16 + l16;
      // S = Q K^T : 16 q-rows x 64 keys
      floatx4 s[4] = {};
#pragma unroll
      for (int kk = 0; kk < 64; kk += 32) {
        const int swz = ((((kk >> 3) + quad) ^ (l16 & 7)) << 3);
#pragma unroll
        for (int j = 0; j < 4; ++j) {
          short8 bk = *reinterpret_cast<const short8*>(
              &Ks[cb][(j * 16 + l16) * 64 + swz]);
          s[j] = __builtin_amdgcn_mfma_f32_16x16x32_bf16(qf[i][kk >> 5], bk,
                                                         s[j], 0, 0, 0);
        }
      }
      if (kt * 64 + 63 > qbase + i * 16 + quad * 4) {  // diagonal: mask
#pragma unroll
        for (int j = 0; j < 4; ++j)
#pragma unroll
          for (int r = 0; r < 4; ++r)
            if (kt * 64 + j * 16 + l16 > qbase + i * 16 + quad * 4 + r)
              s[j][r] = -1e30f;
      }
      // unnormalized exp2 (log2e folded into q); per-lane partial denominators
#pragma unroll
      for (int r = 0; r < 4; ++r) {
        float p0 = fexp2(s[0][r]), p1 = fexp2(s[1][r]);
        float p2 = fexp2(s[2][r]), p3 = fexp2(s[3][r]);
        lsum[i][r] += (p0 + p1) + (p2 + p3);
        const int prow = (wid * 32 + i * 16 + quad * 4 + r) * LDSP + l16;
        unsigned pa = pk2bf(p0, p1), pb = pk2bf(p2, p3);
        Ps[prow]      = (unsigned short)pa;
        Ps[prow + 16] = (unsigned short)(pa >> 16);
        Ps[prow + 32] = (unsigned short)pb;
        Ps[prow + 48] = (unsigned short)(pb >> 16);
      }
      // O += P V (wave-private Ps slab: no barrier needed)
#pragma unroll
      for (int kk = 0; kk < 64; kk += 32) {
        short8 ap = *reinterpret_cast<const short8*>(
            &Ps[arow * LDSP + kk + quad * 8]);
        const int swz = ((((kk >> 3) + quad) ^ (l16 & 7)) << 3);
#pragma unroll
        for (int j = 0; j < 4; ++j) {
          short8 bv = *reinterpret_cast<const short8*>(
              &Vt[cb][(j * 16 + l16) * 64 + swz]);
          o[i][j] = __builtin_amdgcn_mfma_f32_16x16x32_bf16(ap, bv, o[i][j], 0, 0, 0);
        }
      }
    }
  }

  // reduce denominators across 16-lane row groups, normalize, store
#pragma unroll
  for (int i = 0; i < 2; ++i)
#pragma unroll
    for (int r = 0; r < 4; ++r) {
      float ls = lsum[i][r];
#pragma unroll
      for (int off = 1; off < 16; off <<= 1) ls += __shfl_xor(ls, off, 64);
      float inv = 1.f / ls;
      int qrow = qt * 128 + wid * 32 + i * 16 + quad * 4 + r;
#pragma unroll
      for (int j = 0; j < 4; ++j)
        att[((size_t)b * SEQ + qrow) * EMB + h * HDIM + j * 16 + l16] =
            f2bf(o[i][j][r] * inv);
    }
}

extern "C" void kernel_launch(void* const* d_in, const int* in_sizes, int n_in,
                              void* d_out, int out_size, void* d_ws, size_t ws_size,
                              hipStream_t stream) {
  const float* x     = (const float*)d_in[0];
  const float* w_qkv = (const float*)d_in[1];
  const float* b_qkv = (const float*)d_in[2];
  const float* w_out = (const float*)d_in[3];
  const float* b_out = (const float*)d_in[4];
  float* out = (float*)d_out;

  // workspace carve (bf16 as ushort)
  unsigned short* x_bf    = (unsigned short*)d_ws;
  unsigned short* wqkvT   = x_bf + (size_t)ROWS * EMB;          // [3C][C]
  unsigned short* woutT   = wqkvT + (size_t)3 * EMB * EMB;      // [C][C]
  unsigned short* q_bf    = woutT + (size_t)EMB * EMB;          // [B,H,T,D]
  unsigned short* k_bf    = q_bf + (size_t)ROWS * EMB;          // [B,H,T,D]
  unsigned short* v_bf    = k_bf + (size_t)ROWS * EMB;          // [B,H,D,T]
  unsigned short* att_bf  = v_bf + (size_t)ROWS * EMB;          // [B,T,C]

  cvt_kernel<<<(ROWS * EMB / 4) / 256, 256, 0, stream>>>(x, x_bf, ROWS * EMB);
  cvt_T_kernel<<<dim3(3 * EMB / 32, EMB / 32), 256, 0, stream>>>(w_qkv, wqkvT, EMB, 3 * EMB);
  cvt_T_kernel<<<dim3(EMB / 32, EMB / 32), 256, 0, stream>>>(w_out, woutT, EMB, EMB);

  gemm_bf16<0><<<dim3(3 * EMB / BN, ROWS / BM), 256, 0, stream>>>(
      x_bf, wqkvT, b_qkv, q_bf, k_bf, v_bf, nullptr, ROWS, 3 * EMB, EMB);

  attn_kernel<<<dim3(16, HEADS, BATCH), 256, 0, stream>>>(q_bf, k_bf, v_bf, att_bf);

  gemm_bf16<1><<<dim3(EMB / BN, ROWS / BM), 256, 0, stream>>>(
      att_bf, woutT, b_out, nullptr, nullptr, nullptr, out, ROWS, EMB, EMB);
}

// Round 7
// 257.400 us; speedup vs baseline: 1.1905x; 1.1905x over previous
//
#include <hip/hip_runtime.h>

typedef __attribute__((ext_vector_type(8))) short short8;
typedef __attribute__((ext_vector_type(4))) float floatx4;

#define EMB 1024
#define HEADS 16
#define HDIM 64
#define BATCH 4
#define SEQ 2048
#define ROWS (BATCH * SEQ)   // 8192

__device__ __forceinline__ unsigned short f2bf(float f) {
  unsigned u = __float_as_uint(f);
  u += 0x7fffu + ((u >> 16) & 1u);   // round-to-nearest-even
  return (unsigned short)(u >> 16);
}

__device__ __forceinline__ unsigned pk2bf(float lo, float hi) {
#if __has_builtin(__builtin_amdgcn_cvt_pk_bf16_f32)
  auto v = __builtin_amdgcn_cvt_pk_bf16_f32(lo, hi);
  return __builtin_bit_cast(unsigned, v);
#else
  return (unsigned)f2bf(lo) | ((unsigned)f2bf(hi) << 16);
#endif
}

__device__ __forceinline__ float fexp2(float x) {
#if __has_builtin(__builtin_amdgcn_exp2f)
  return __builtin_amdgcn_exp2f(x);
#else
  return __builtin_exp2f(x);
#endif
}

__device__ __forceinline__ void gload16(const void* g, void* l) {
  __builtin_amdgcn_global_load_lds(
      (const __attribute__((address_space(1))) unsigned int*)g,
      (__attribute__((address_space(3))) unsigned int*)l, 16, 0, 0);
}

// ---------------- fp32 -> bf16 convert (row-major copy) ----------------
__global__ void cvt_kernel(const float* __restrict__ in,
                           unsigned short* __restrict__ out, int n) {
  int i = (blockIdx.x * blockDim.x + threadIdx.x) * 4;
  if (i < n) {
    float4 f = *reinterpret_cast<const float4*>(in + i);
    ushort4 o;
    o.x = f2bf(f.x); o.y = f2bf(f.y); o.z = f2bf(f.z); o.w = f2bf(f.w);
    *reinterpret_cast<ushort4*>(out + i) = o;
  }
}

// ---------------- fp32 [R][C] -> bf16 [C][R] transpose ----------------
__global__ __launch_bounds__(256) void cvt_T_kernel(
    const float* __restrict__ in, unsigned short* __restrict__ out, int R, int C) {
  __shared__ float t[32][33];
  const int tx = threadIdx.x & 31, ty = threadIdx.x >> 5;  // 32 x 8
  const int c0 = blockIdx.x * 32, r0 = blockIdx.y * 32;
#pragma unroll
  for (int j = 0; j < 4; ++j)
    t[ty + j * 8][tx] = in[(size_t)(r0 + ty + j * 8) * C + c0 + tx];
  __syncthreads();
#pragma unroll
  for (int j = 0; j < 4; ++j)
    out[(size_t)(c0 + ty + j * 8) * R + r0 + tx] = f2bf(t[tx][ty + j * 8]);
}

// ---------------- bf16 MFMA GEMM: C = A[M,K] @ Bt[N,K]^T + bias ----------------
// LDS XOR-swizzled (octet ^= row&7): staging stays contiguous-per-lane (gload16
// requirement), fragment b128 reads spread across all 32 banks (measured: 0 conflicts).
// EPI=0: scatter q/k [B,H,T,D] (q scaled 0.125*log2e), v transposed [B,H,D,T].
// EPI=1: fp32 out.
#define BM 128
#define BN 128
#define BK 64
#define QSCALE 0.18033688011116016f   // 0.125 * log2(e): softmax via exp2

template <int EPI>
__global__ __launch_bounds__(256) void gemm_bf16(
    const unsigned short* __restrict__ A, const unsigned short* __restrict__ Bt,
    const float* __restrict__ bias,
    unsigned short* __restrict__ qo, unsigned short* __restrict__ ko,
    unsigned short* __restrict__ vo, float* __restrict__ fo,
    int M, int N, int K) {
  __shared__ unsigned short Al[BM * BK];   // [row][k], unpadded, swizzled
  __shared__ unsigned short Bl[BN * BK];   // [n][k], unpadded, swizzled
  const int tid = threadIdx.x;
  const int wid = tid >> 6, lane = tid & 63;
  const int quad = lane >> 4, l16 = lane & 15;
  const int wr = wid >> 1, wc = wid & 1;
  const int bm = blockIdx.y * BM, bn = blockIdx.x * BN;
  const int lrow = lane >> 3;                   // staging row within 8-row chunk
  const int srow = wid * 8 + lrow;              // staging row within 32-row slab
  const int soct = ((lane & 7) ^ lrow) * 8;     // XOR-swizzled source k-octet

  floatx4 acc[4][4] = {};

  for (int k0 = 0; k0 < K; k0 += BK) {
    __syncthreads();
#pragma unroll
    for (int it = 0; it < 4; ++it) {
      gload16(&A[(size_t)(bm + it * 32 + srow) * K + k0 + soct],
              &Al[(wid * 8 + it * 32) * BK]);
      gload16(&Bt[(size_t)(bn + it * 32 + srow) * K + k0 + soct],
              &Bl[(wid * 8 + it * 32) * BK]);
    }
    __syncthreads();
#pragma unroll
    for (int kk = 0; kk < BK; kk += 32) {
      const int swz = ((((kk >> 3) + quad) ^ (l16 & 7)) << 3);
      short8 af[4], bfv[4];
#pragma unroll
      for (int i = 0; i < 4; ++i)
        af[i] = *reinterpret_cast<const short8*>(
            &Al[(wr * 64 + i * 16 + l16) * BK + swz]);
#pragma unroll
      for (int j = 0; j < 4; ++j)
        bfv[j] = *reinterpret_cast<const short8*>(
            &Bl[(wc * 64 + j * 16 + l16) * BK + swz]);
#pragma unroll
      for (int i = 0; i < 4; ++i)
#pragma unroll
        for (int j = 0; j < 4; ++j)
          acc[i][j] = __builtin_amdgcn_mfma_f32_16x16x32_bf16(af[i], bfv[j],
                                                              acc[i][j], 0, 0, 0);
    }
  }

  // epilogue: D[row=quad*4+r][col=l16] per 16x16 tile
#pragma unroll
  for (int j = 0; j < 4; ++j) {
    const int n = bn + wc * 64 + j * 16 + l16;
    const float bv = bias[n];
    if (EPI == 0) {
      const int which = n >> 10, cc = n & 1023;
      const int hh = cc >> 6, dd = cc & 63;
#pragma unroll
      for (int i = 0; i < 4; ++i) {
        const int m0 = bm + wr * 64 + i * 16 + quad * 4;
        const int bb = m0 >> 11, tt = m0 & 2047;
        if (which == 2) {
          ushort4 pk;
          pk.x = f2bf(acc[i][j][0] + bv);
          pk.y = f2bf(acc[i][j][1] + bv);
          pk.z = f2bf(acc[i][j][2] + bv);
          pk.w = f2bf(acc[i][j][3] + bv);
          *reinterpret_cast<ushort4*>(
              &vo[(((size_t)bb * HEADS + hh) * HDIM + dd) * SEQ + tt]) = pk;
        } else {
          unsigned short* dst = (which == 0) ? qo : ko;
          const float sc = (which == 0) ? QSCALE : 1.0f;
          const size_t base = (((size_t)bb * HEADS + hh) * SEQ + tt) * HDIM + dd;
#pragma unroll
          for (int r = 0; r < 4; ++r)
            dst[base + (size_t)r * HDIM] = f2bf((acc[i][j][r] + bv) * sc);
        }
      }
    } else {
#pragma unroll
      for (int i = 0; i < 4; ++i) {
        const int m0 = bm + wr * 64 + i * 16 + quad * 4;
#pragma unroll
        for (int r = 0; r < 4; ++r)
          fo[(size_t)(m0 + r) * N + n] = acc[i][j][r] + bv;
      }
    }
  }
}

// ---------------- flash attention (causal, unnormalized exp2 softmax) --------------
// 512-thread blocks (8 waves x 16 q-rows = 128-row q-tile), q-tiles PAIRED
// (15-p, p): constant 34 k-tile units per block -> 512 perfectly balanced blocks,
// 2 blocks/CU (LDS 52,224 B) = 16 waves/CU. Q fragments in registers (both halves
// preloaded). K/V double-buffered, one barrier per k-tile; half 2's tile-0 staging
// issued before half 1's epilogue (overlaps load latency with reduction/stores).
#define LDSP 76
__global__ __launch_bounds__(512, 4) void attn_kernel(
    const unsigned short* __restrict__ q, const unsigned short* __restrict__ k,
    const unsigned short* __restrict__ vt, unsigned short* __restrict__ att) {
  __shared__ unsigned short Ks[2][64 * 64];
  __shared__ unsigned short Vt[2][64 * 64];  // [d][key]
  __shared__ unsigned short Ps[128 * LDSP];  // [q][key], wave-private 16-row slabs
  const int tid = threadIdx.x, wid = tid >> 6, lane = tid & 63;
  const int quad = lane >> 4, l16 = lane & 15;
  const int srow = lane >> 3;                       // row within wave's 8-row slab
  const int soct = ((lane & 7) ^ srow) * 8;         // XOR-swizzled source octet
  const int rowK = wid * 8 + srow;                  // staging row 0..63
  const int p = blockIdx.x;                         // pair index 0..7
  const int h = blockIdx.y, b = blockIdx.z;
  const size_t hb = ((size_t)b * HEADS + h) * SEQ * HDIM;  // q,k row base
  const size_t hv = ((size_t)b * HEADS + h) * HDIM * SEQ;  // vt row base
  const int qts[2] = {15 - p, p};                   // heavy half first

  // Q fragments for BOTH halves, direct to registers:
  // A[m=l16][k=quad*8+j] is a contiguous 16B chunk of the global [T,D] row.
  short8 qf[2][2];
#pragma unroll
  for (int hh2 = 0; hh2 < 2; ++hh2)
#pragma unroll
    for (int c = 0; c < 2; ++c)
      qf[hh2][c] = *reinterpret_cast<const short8*>(
          &q[hb + (size_t)(qts[hh2] * 128 + wid * 16 + l16) * HDIM + c * 32 + quad * 8]);

  // stage K/V tile 0 of half 0 into buf 0 (one gload16 per thread per array)
  gload16(&k[hb + (size_t)rowK * HDIM + soct], &Ks[0][wid * 8 * 64]);
  gload16(&vt[hv + (size_t)rowK * SEQ + soct], &Vt[0][wid * 8 * 64]);

  for (int half = 0; half < 2; ++half) {
    const int qt = qts[half];
    const int qbase = qt * 128 + wid * 16;   // this wave's first q row

    floatx4 o[4] = {};
    float lsum[4] = {};

    const int ntile = 2 * qt + 2;
    for (int kt = 0; kt < ntile; ++kt) {
      __syncthreads();  // buf[kt&1] staged (per-wave vmcnt drained); prior readers done
      if (kt + 1 < ntile) {   // prefetch next tile into the other buffer
        const int nb = (kt + 1) & 1;
        gload16(&k[hb + (size_t)((kt + 1) * 64 + rowK) * HDIM + soct],
                &Ks[nb][wid * 8 * 64]);
        gload16(&vt[hv + (size_t)rowK * SEQ + (kt + 1) * 64 + soct],
                &Vt[nb][wid * 8 * 64]);
      }
      if (kt * 64 > qbase + 15) continue;   // wave fully masked this k-tile
      const int cb = kt & 1;

      // S = Q K^T : 16 q-rows x 64 keys
      floatx4 s[4] = {};
#pragma unroll
      for (int kk = 0; kk < 64; kk += 32) {
        const int swz = ((((kk >> 3) + quad) ^ (l16 & 7)) << 3);
#pragma unroll
        for (int j = 0; j < 4; ++j) {
          short8 bk = *reinterpret_cast<const short8*>(
              &Ks[cb][(j * 16 + l16) * 64 + swz]);
          s[j] = __builtin_amdgcn_mfma_f32_16x16x32_bf16(qf[half][kk >> 5], bk,
                                                         s[j], 0, 0, 0);
        }
      }
      if (kt * 64 + 63 > qbase + quad * 4) {  // diagonal: mask
#pragma unroll
        for (int j = 0; j < 4; ++j)
#pragma unroll
          for (int r = 0; r < 4; ++r)
            if (kt * 64 + j * 16 + l16 > qbase + quad * 4 + r)
              s[j][r] = -1e30f;
      }
      // unnormalized exp2 (log2e folded into q); per-lane partial denominators
#pragma unroll
      for (int r = 0; r < 4; ++r) {
        float p0 = fexp2(s[0][r]), p1 = fexp2(s[1][r]);
        float p2 = fexp2(s[2][r]), p3 = fexp2(s[3][r]);
        lsum[r] += (p0 + p1) + (p2 + p3);
        const int prow = (wid * 16 + quad * 4 + r) * LDSP + l16;
        unsigned pa = pk2bf(p0, p1), pb = pk2bf(p2, p3);
        Ps[prow]      = (unsigned short)pa;
        Ps[prow + 16] = (unsigned short)(pa >> 16);
        Ps[prow + 32] = (unsigned short)pb;
        Ps[prow + 48] = (unsigned short)(pb >> 16);
      }
      // O += P V (wave-private Ps slab: no barrier needed)
#pragma unroll
      for (int kk = 0; kk < 64; kk += 32) {
        short8 ap = *reinterpret_cast<const short8*>(
            &Ps[(wid * 16 + l16) * LDSP + kk + quad * 8]);
        const int swz = ((((kk >> 3) + quad) ^ (l16 & 7)) << 3);
#pragma unroll
        for (int j = 0; j < 4; ++j) {
          short8 bv = *reinterpret_cast<const short8*>(
              &Vt[cb][(j * 16 + l16) * 64 + swz]);
          o[j] = __builtin_amdgcn_mfma_f32_16x16x32_bf16(ap, bv, o[j], 0, 0, 0);
        }
      }
    }

    // Before the epilogue: issue half 2's tile-0 staging into buf0. Safe: every
    // wave passed the last k-iter's barrier, which implies all buf0 compute done
    // (last tile is odd-indexed -> buf1). Completion awaited at next half's kt=0
    // barrier, overlapping load latency with the epilogue below.
    if (half == 0) {
      gload16(&k[hb + (size_t)rowK * HDIM + soct], &Ks[0][wid * 8 * 64]);
      gload16(&vt[hv + (size_t)rowK * SEQ + soct], &Vt[0][wid * 8 * 64]);
    }

    // reduce denominators across 16-lane row groups, normalize, store
#pragma unroll
    for (int r = 0; r < 4; ++r) {
      float ls = lsum[r];
#pragma unroll
      for (int off = 1; off < 16; off <<= 1) ls += __shfl_xor(ls, off, 64);
      float inv = 1.f / ls;
      int qrow = qt * 128 + wid * 16 + quad * 4 + r;
#pragma unroll
      for (int j = 0; j < 4; ++j)
        att[((size_t)b * SEQ + qrow) * EMB + h * HDIM + j * 16 + l16] =
            f2bf(o[j][r] * inv);
    }
  }
}

extern "C" void kernel_launch(void* const* d_in, const int* in_sizes, int n_in,
                              void* d_out, int out_size, void* d_ws, size_t ws_size,
                              hipStream_t stream) {
  const float* x     = (const float*)d_in[0];
  const float* w_qkv = (const float*)d_in[1];
  const float* b_qkv = (const float*)d_in[2];
  const float* w_out = (const float*)d_in[3];
  const float* b_out = (const float*)d_in[4];
  float* out = (float*)d_out;

  // workspace carve (bf16 as ushort)
  unsigned short* x_bf    = (unsigned short*)d_ws;
  unsigned short* wqkvT   = x_bf + (size_t)ROWS * EMB;          // [3C][C]
  unsigned short* woutT   = wqkvT + (size_t)3 * EMB * EMB;      // [C][C]
  unsigned short* q_bf    = woutT + (size_t)EMB * EMB;          // [B,H,T,D]
  unsigned short* k_bf    = q_bf + (size_t)ROWS * EMB;          // [B,H,T,D]
  unsigned short* v_bf    = k_bf + (size_t)ROWS * EMB;          // [B,H,D,T]
  unsigned short* att_bf  = v_bf + (size_t)ROWS * EMB;          // [B,T,C]

  cvt_kernel<<<(ROWS * EMB / 4) / 256, 256, 0, stream>>>(x, x_bf, ROWS * EMB);
  cvt_T_kernel<<<dim3(3 * EMB / 32, EMB / 32), 256, 0, stream>>>(w_qkv, wqkvT, EMB, 3 * EMB);
  cvt_T_kernel<<<dim3(EMB / 32, EMB / 32), 256, 0, stream>>>(w_out, woutT, EMB, EMB);

  gemm_bf16<0><<<dim3(3 * EMB / BN, ROWS / BM), 256, 0, stream>>>(
      x_bf, wqkvT, b_qkv, q_bf, k_bf, v_bf, nullptr, ROWS, 3 * EMB, EMB);

  attn_kernel<<<dim3(8, HEADS, BATCH), 512, 0, stream>>>(q_bf, k_bf, v_bf, att_bf);

  gemm_bf16<1><<<dim3(EMB / BN, ROWS / BM), 256, 0, stream>>>(
      att_bf, woutT, b_out, nullptr, nullptr, nullptr, out, ROWS, EMB, EMB);
}